// Round 10
// baseline (363.763 us; speedup 1.0000x reference)
//
#include <hip/hip_runtime.h>
#include <hip/hip_bf16.h>
#include <math.h>

#define NROW 8192
#define DDIM 256
#define NPAIR 2080      // 64*65/2 tile pairs (by >= bx)

typedef __attribute__((ext_vector_type(4))) float f32x4;
typedef __attribute__((ext_vector_type(4))) int   i32x4;
typedef __attribute__((ext_vector_type(8))) int   i32x8;
typedef __attribute__((address_space(3))) unsigned int lds_u32;
typedef const __attribute__((address_space(1))) unsigned int glb_u32;

// DPP row_ror butterfly add: after ror 1,2,4,8 every lane of each 16-lane row
// holds the row sum. VALU pipe only — no DS traffic.
template <int CTRL>
static __device__ inline float dpp_ror_add(float v) {
    int s = __float_as_int(v);
    int r = __builtin_amdgcn_update_dpp(0, s, CTRL, 0xF, 0xF, true);
    return v + __int_as_float(r);
}
static __device__ inline float row16_sum(float v) {
    v = dpp_ror_add<0x121>(v);
    v = dpp_ror_add<0x122>(v);
    v = dpp_ror_add<0x124>(v);
    v = dpp_ror_add<0x128>(v);
    return v;
}

// Pack 4 floats -> 4 fp8 e4m3 bytes (HW cvt, OCP on gfx950).
static __device__ inline unsigned int pack_fp8x4(float a, float b, float c, float d) {
    int p = __builtin_amdgcn_cvt_pk_fp8_f32(a, b, 0, false);
    p = __builtin_amdgcn_cvt_pk_fp8_f32(c, d, p, true);
    return (unsigned int)p;
}

// TILED z layout for the K=128 scaled MFMA: storage block SB(g,h) = 2048 B at
// g*4096 + h*2048 (g = 16-row group, h = K-128 half). Within SB: byte
// u*1024 + (quad*16 + rr)*16 + b  holds  z[16g+rr][h*128 + quad*32 + u*16 + b]
// — so lane L = quad*16+rr of a wave reads its 32-contiguous-k A/B fragment
// as TWO lane-linear b128s (base + L*16 and base + 1024 + L*16): the R8-proven
// zero-conflict pattern, and each (g,h,u) sub-block is one contiguous 1-KB
// coalesced DMA. One wave per row; lane holds k0=4*lane..+3 -> one u32 store.
// diag[row] = 2*dot(z1n,z2n) fp32 (exact). Zero-inits rowsums and out.
__global__ __launch_bounds__(256) void normalize_kernel(
        const float* __restrict__ h1, const float* __restrict__ h2,
        unsigned int* __restrict__ z1b, unsigned int* __restrict__ z2b,
        float* __restrict__ diag,
        float* __restrict__ rs1, float* __restrict__ rs2,
        float* __restrict__ rbr, float* __restrict__ rbc,
        float* __restrict__ out) {
    int wave = threadIdx.x >> 6;
    int lane = threadIdx.x & 63;
    int row  = blockIdx.x * 4 + wave;
    if (blockIdx.x == 0 && threadIdx.x == 0) out[0] = 0.f;
    const float4* p1 = (const float4*)(h1 + (size_t)row * DDIM);
    const float4* p2 = (const float4*)(h2 + (size_t)row * DDIM);
    float4 a = p1[lane];
    float4 b = p2[lane];
    float s1 = a.x*a.x + a.y*a.y + a.z*a.z + a.w*a.w;
    float s2 = b.x*b.x + b.y*b.y + b.z*b.z + b.w*b.w;
    #pragma unroll
    for (int m = 1; m < 64; m <<= 1) { s1 += __shfl_xor(s1, m); s2 += __shfl_xor(s2, m); }
    float r1 = 1.0f / fmaxf(sqrtf(s1), 1e-12f);
    float r2 = 1.0f / fmaxf(sqrtf(s2), 1e-12f);
    float n1x = a.x*r1, n1y = a.y*r1, n1z = a.z*r1, n1w = a.w*r1;
    float n2x = b.x*r2, n2y = b.y*r2, n2z = b.z*r2, n2w = b.w*r2;
    float dt = n1x*n2x + n1y*n2y + n1z*n2z + n1w*n2w;
    #pragma unroll
    for (int m = 1; m < 64; m <<= 1) dt += __shfl_xor(dt, m);
    if (lane == 0) {
        diag[row] = 2.0f * dt;
        rs1[row] = 0.f; rs2[row] = 0.f; rbr[row] = 0.f; rbc[row] = 0.f;
    }
    // k0 = 4*lane -> (h, quad, u, c4):
    int h    = lane >> 5;
    int quad = (lane >> 3) & 3;
    int u    = (lane >> 2) & 1;
    int c4   = lane & 3;
    int g    = row >> 4, rr = row & 15;
    int pw   = g * 1024 + h * 512 + u * 256 + (quad * 16 + rr) * 4 + c4;  // u32 idx
    const float SC = 1.69864364f;   // sqrt(2 * log2(e))
    z1b[pw] = pack_fp8x4(n1x*SC, n1y*SC, n1z*SC, n1w*SC);
    z2b[pw] = pack_fp8x4(n2x*SC, n2y*SC, n2z*SC, n2w*SC);
}

// PAIR-BLOCK kernel: block p handles tile-pair (by >= bx) and computes FOUR
// 128x128 Gram tiles from the same 4 staged strips:
//   g0: S11(by,bx)  A=z1[by] B=z1[bx]  -> rs1 rows (+cols if by!=bx)
//   g1: S22(by,bx)  A=z2[by] B=z2[bx]  -> rs2
//   g2: S12(by,bx)  A=z1[by] B=z2[bx]  -> rbr rows, rbc cols
//   g3: S12(bx,by)  A=z1[bx] B=z2[by]  -> rbr/rbc (suppressed when by==bx)
// 16 waves (4 per tile), 64 KB LDS per K-128 half, K=128 scaled MFMA with
// unit E8M0 scales (R6-validated). 4x fewer barrier/drain events and half
// the DMA instructions per MFMA vs the R8 per-tile structure.
__global__ __launch_bounds__(1024, 4) void expsum_kernel(
        const unsigned char* __restrict__ z1, const unsigned char* __restrict__ z2,
        float* __restrict__ rs1, float* __restrict__ rs2,
        float* __restrict__ rbr, float* __restrict__ rbc) {
    int p = blockIdx.x;
    int by = (int)((sqrtf(8.0f * (float)p + 1.0f) - 1.0f) * 0.5f);
    while ((by + 1) * (by + 2) / 2 <= p) ++by;
    while (by * (by + 1) / 2 > p) --by;
    int bx = p - by * (by + 1) / 2;          // bx <= by
    bool diag = (by == bx);

    __shared__ __align__(16) unsigned char lS[4 * 16384];   // 64 KB: 4 strips

    const int tid  = threadIdx.x;
    const int lane = tid & 63;
    const int wid  = tid >> 6;     // 0..15
    const int g    = wid >> 2;     // tile-group
    const int sw   = wid & 3;
    const int wr   = sw >> 1;
    const int wc   = sw & 1;
    const int quad = lane >> 4;
    const int l15  = lane & 15;

    // strips: 0=z1[by], 1=z1[bx], 2=z2[by], 3=z2[bx]
    int sa, sb, rt2, ct2;
    float *rsum, *csum;
    if (g == 0)      { sa = 0; sb = 1; rsum = rs1; csum = diag ? nullptr : rs1;
                       rt2 = by * 128; ct2 = bx * 128; }
    else if (g == 1) { sa = 2; sb = 3; rsum = rs2; csum = diag ? nullptr : rs2;
                       rt2 = by * 128; ct2 = bx * 128; }
    else if (g == 2) { sa = 0; sb = 3; rsum = rbr; csum = rbc;
                       rt2 = by * 128; ct2 = bx * 128; }
    else             { sa = 1; sb = 2; rsum = diag ? nullptr : rbr;
                       csum = diag ? nullptr : rbc;
                       rt2 = bx * 128; ct2 = by * 128; }

    f32x4 acc[4][4];
    #pragma unroll
    for (int mi = 0; mi < 4; ++mi)
        #pragma unroll
        for (int ni = 0; ni < 4; ++ni)
            acc[mi][ni] = (f32x4){0.f, 0.f, 0.f, 0.f};

    const unsigned char* aB = lS + sa * 16384 + (wr * 4) * 2048;
    const unsigned char* bB = lS + sb * 16384 + (wc * 4) * 2048;

    for (int h = 0; h < 2; ++h) {            // two K-128 halves
        if (h) __syncthreads();              // prior half's LDS reads done
        // Stage 4 strips x 16 KB: 64 1-KB DMA blocks, 4 per wave.
        #pragma unroll
        for (int i = 0; i < 4; ++i) {
            int bi = i * 16 + wid;           // 0..63
            int s  = bi >> 4;
            int rem = bi & 15;
            int sg = rem >> 1, u = rem & 1;
            const unsigned char* zp = (s < 2) ? z1 : z2;
            int Rv = (s & 1) ? bx : by;
            const unsigned char* src = zp + ((size_t)(Rv * 8 + sg)) * 4096
                                          + h * 2048 + u * 1024 + lane * 16;
            __builtin_amdgcn_global_load_lds((glb_u32*)src,
                (lds_u32*)(lS + s * 16384 + sg * 2048 + u * 1024), 16, 0, 0);
        }
        __syncthreads();

        i32x8 af[4], bf[4];
        #pragma unroll
        for (int mi = 0; mi < 4; ++mi) {
            i32x4 lo = *((const i32x4*)(aB + mi * 2048 + lane * 16));
            i32x4 hi = *((const i32x4*)(aB + mi * 2048 + 1024 + lane * 16));
            af[mi] = __builtin_shufflevector(lo, hi, 0, 1, 2, 3, 4, 5, 6, 7);
        }
        #pragma unroll
        for (int ni = 0; ni < 4; ++ni) {
            i32x4 lo = *((const i32x4*)(bB + ni * 2048 + lane * 16));
            i32x4 hi = *((const i32x4*)(bB + ni * 2048 + 1024 + lane * 16));
            bf[ni] = __builtin_shufflevector(lo, hi, 0, 1, 2, 3, 4, 5, 6, 7);
        }
        #pragma unroll
        for (int mi = 0; mi < 4; ++mi)
            #pragma unroll
            for (int ni = 0; ni < 4; ++ni)
                acc[mi][ni] = __builtin_amdgcn_mfma_scale_f32_16x16x128_f8f6f4(
                    af[mi], bf[ni], acc[mi][ni],
                    0, 0,                    // cbsz/blgp = fp8 e4m3
                    0, 0x7F7F7F7F,           // unit E8M0 scales
                    0, 0x7F7F7F7F);
    }

    // C/D layout: col = lane&15, row = quad*4 + reg. acc = 2*log2e*s -> exp2.
    float colpart[4] = {0.f, 0.f, 0.f, 0.f};
    #pragma unroll
    for (int mi = 0; mi < 4; ++mi) {
        #pragma unroll
        for (int r = 0; r < 4; ++r) {
            float rp = 0.f;
            #pragma unroll
            for (int ni = 0; ni < 4; ++ni) {
                float e = exp2f(acc[mi][ni][r]);
                rp += e;
                colpart[ni] += e;
            }
            rp = row16_sum(rp);          // DPP, VALU-pipe only
            if (rsum && l15 == 0) {
                int grow = rt2 + wr * 64 + mi * 16 + quad * 4 + r;
                atomicAdd(&rsum[grow], rp);
            }
        }
    }
    if (csum) {
        #pragma unroll
        for (int ni = 0; ni < 4; ++ni) {
            float cp = colpart[ni];
            cp += __shfl_xor(cp, 16);
            cp += __shfl_xor(cp, 32);
            if (lane < 16) {
                int gcol = ct2 + wc * 64 + ni * 16 + l15;
                atomicAdd(&csum[gcol], cp);
            }
        }
    }
}

// 32 blocks x 256 threads, one row each; block-reduce then one atomicAdd.
__global__ __launch_bounds__(256) void finalize_kernel(
        const float* __restrict__ rs1, const float* __restrict__ rs2,
        const float* __restrict__ rbr, const float* __restrict__ rbc,
        const float* __restrict__ diag, float* __restrict__ out) {
    __shared__ float s4[4];
    const float E2 = 7.38905609893065f;   // exp(1/tau), tau=0.5
    int i = blockIdx.x * 256 + threadIdx.x;
    float den1 = rs1[i] + rbr[i] - E2;
    float den2 = rs2[i] + rbc[i] - E2;
    float v = 0.5f * (logf(den1) + logf(den2)) - diag[i];
    #pragma unroll
    for (int m = 1; m < 64; m <<= 1) v += __shfl_xor(v, m);
    if ((threadIdx.x & 63) == 0) s4[threadIdx.x >> 6] = v;
    __syncthreads();
    if (threadIdx.x == 0) {
        float t = (s4[0] + s4[1] + s4[2] + s4[3]) * (1.0f / (float)NROW);
        atomicAdd(out, t);
    }
}

extern "C" void kernel_launch(void* const* d_in, const int* in_sizes, int n_in,
                              void* d_out, int out_size, void* d_ws, size_t ws_size,
                              hipStream_t stream) {
    const float* h1 = (const float*)d_in[0];
    const float* h2 = (const float*)d_in[1];
    float* out = (float*)d_out;

    char* ws = (char*)d_ws;
    unsigned char* z1b = (unsigned char*)ws;                             // 2 MB
    unsigned char* z2b = (unsigned char*)(ws + (size_t)NROW * DDIM);     // 2 MB
    float* sums = (float*)(ws + (size_t)2 * NROW * DDIM);
    float* rs1  = sums;
    float* rs2  = sums + NROW;
    float* rbr  = sums + 2 * NROW;
    float* rbc  = sums + 3 * NROW;
    float* diag = sums + 4 * NROW;

    normalize_kernel<<<NROW / 4, 256, 0, stream>>>(h1, h2,
                                                   (unsigned int*)z1b, (unsigned int*)z2b,
                                                   diag, rs1, rs2, rbr, rbc, out);

    expsum_kernel<<<NPAIR, 1024, 0, stream>>>(z1b, z2b, rs1, rs2, rbr, rbc);

    finalize_kernel<<<NROW / 256, 256, 0, stream>>>(rs1, rs2, rbr, rbc, diag, out);
}